// Round 2
// baseline (1101.276 us; speedup 1.0000x reference)
//
#include <hip/hip_runtime.h>

// CRF NLL forward loss. B=256, T=2048, K2=52 (50 labels + START=50 + STOP=51).
// Linear-domain forward recurrence: one wave per batch, no LDS, no barriers.
//   g_{t+1} = (M2 . g_t) * E_t / m_t,   C += log2(m_t),  m_t = max(g_t)
// where M2[n][p] = 2^(tr[n][p]*log2e) is precomputed in 52 VGPRs per lane.

#define B_    256
#define T_    2048
#define K2_   52
#define PF    4
#define LOG2E_ 1.4426950408889634f
#define LN2_   0.6931471805599453f

__device__ __forceinline__ float rdlane(float v, int src) {
  return __uint_as_float(__builtin_amdgcn_readlane(__float_as_uint(v), src));
}

__launch_bounds__(64, 1)
__global__ void crf_fwd_kernel(const float* __restrict__ em,
                               const float* __restrict__ tr,
                               const int*  __restrict__ len,
                               const int*  __restrict__ lab,
                               float* __restrict__ per_b)
{
  const int b    = blockIdx.x;
  const int lane = threadIdx.x;                      // 64
  const int n    = (lane < K2_) ? lane : (K2_ - 1);  // lanes 52..63 mirror lane 51 (harmless)
  const int L    = len[b];
  const float* emb = em + (size_t)b * (T_ * K2_);

  // Row n of exp2-transitions, resident in VGPRs.
  float M2[K2_];
#pragma unroll
  for (int p = 0; p < K2_; ++p)
    M2[p] = __builtin_amdgcn_exp2f(tr[n * K2_ + p] * LOG2E_);

  // linear-domain state; true alpha_exp = g * 2^C
  float g = (lane == K2_ - 2) ? 1.0f : 0.0f;
  float C = 0.0f;

  // emission prefetch ring (rows t..t+PF-1)
  float pf[PF];
#pragma unroll
  for (int i = 0; i < PF; ++i)
    pf[i] = emb[i * K2_ + n];

  for (int t = 0; t < L; ++t) {
    float emv = pf[t & (PF - 1)];
    int tp = t + PF; if (tp > T_ - 1) tp = T_ - 1;
    pf[t & (PF - 1)] = emb[tp * K2_ + n];            // refill ring (no barrier -> stays in flight)

    // wave-max of g — independent of the matvec below; scheduler overlaps them
    float m = g;
#pragma unroll
    for (int off = 32; off >= 1; off >>= 1)
      m = fmaxf(m, __shfl_xor(m, off, 64));
    float inv = __builtin_amdgcn_rcpf(m);

    // y[n] = sum_p M2[n][p] * g[p]   (broadcast via v_readlane, 4 acc chains)
    float a0 = 0.0f, a1 = 0.0f, a2 = 0.0f, a3 = 0.0f;
#pragma unroll
    for (int p = 0; p < K2_; p += 4) {
      a0 = fmaf(M2[p + 0], rdlane(g, p + 0), a0);
      a1 = fmaf(M2[p + 1], rdlane(g, p + 1), a1);
      a2 = fmaf(M2[p + 2], rdlane(g, p + 2), a2);
      a3 = fmaf(M2[p + 3], rdlane(g, p + 3), a3);
    }
    float y = (a0 + a1) + (a2 + a3);

    float E = __builtin_amdgcn_exp2f(emv * LOG2E_);
    g = y * E * inv;
    C += __builtin_amdgcn_logf(m);                   // v_log_f32 = log2
  }

  // terminal: fwd = ln2 * (C + log2 sum_p g_p * 2^(tr2[STOP][p]))
  float stopv = (lane < K2_)
      ? g * __builtin_amdgcn_exp2f(tr[(K2_ - 1) * K2_ + n] * LOG2E_)
      : 0.0f;
#pragma unroll
  for (int off = 32; off >= 1; off >>= 1)
    stopv += __shfl_xor(stopv, off, 64);
  float fwd = (C + __builtin_amdgcn_logf(stopv)) * LN2_;

  // gold score (raw log domain)
  float gold = 0.0f;
  const int* labb = lab + b * T_;
  for (int t = lane; t < L; t += 64) {
    int l1 = labb[t];
    int l0 = (t == 0) ? (K2_ - 2) : labb[t - 1];
    gold += emb[t * K2_ + l1] + tr[l1 * K2_ + l0];
  }
  if (lane == 0) gold += tr[(K2_ - 1) * K2_ + labb[L - 1]];  // STOP <- last label
#pragma unroll
  for (int off = 32; off >= 1; off >>= 1)
    gold += __shfl_xor(gold, off, 64);

  if (lane == 0) per_b[b] = fwd - gold;
}

__global__ void reduce_mean_kernel(const float* __restrict__ per_b,
                                   float* __restrict__ out)
{
  const int tid = threadIdx.x;  // 256
  float v = per_b[tid];
#pragma unroll
  for (int off = 32; off >= 1; off >>= 1) v += __shfl_xor(v, off, 64);
  __shared__ float s[4];
  if ((tid & 63) == 0) s[tid >> 6] = v;
  __syncthreads();
  if (tid == 0) out[0] = ((s[0] + s[1]) + (s[2] + s[3])) * (1.0f / (float)B_);
}

extern "C" void kernel_launch(void* const* d_in, const int* in_sizes, int n_in,
                              void* d_out, int out_size, void* d_ws, size_t ws_size,
                              hipStream_t stream) {
  const float* em  = (const float*)d_in[0];   // [B,T,K2] f32
  const float* tr  = (const float*)d_in[1];   // [K2,K2]  f32
  const int*   len = (const int*)d_in[2];     // [B] i32
  const int*   lab = (const int*)d_in[3];     // [B,T] i32
  float* out = (float*)d_out;
  float* ws  = (float*)d_ws;                  // 256 floats of per-batch scores

  crf_fwd_kernel<<<B_, 64, 0, stream>>>(em, tr, len, lab, ws);
  reduce_mean_kernel<<<1, 256, 0, stream>>>(ws, out);
}